// Round 13
// baseline (7482.726 us; speedup 1.0000x reference)
//
#include <hip/hip_runtime.h>

#define B_ 256
#define T_ 1024
#define H_ 64

typedef float f32x2 __attribute__((ext_vector_type(2)));
typedef float f32x4 __attribute__((ext_vector_type(4)));

// fast sigmoid/tanh via v_exp_f32 + v_rcp_f32 (validated R2-R12: absmax 0.0)
__device__ __forceinline__ float fast_tanh(float x) {
    float e = __builtin_amdgcn_exp2f(2.8853900817779268f * x);
    return 1.0f - 2.0f * __builtin_amdgcn_rcpf(1.0f + e);
}

// R13: lane-split branchless gate activation. Lane kc handles gate kc.
// sigmoid(v) = rcp(1+exp2(-log2e*v)); tanh(v) = 2*rcp(1+exp2(-2*log2e*v)) - 1.
// Per-lane constants (scl,mulk,offk) picked ONCE outside the loop.
__device__ __forceinline__ float gate_act(float v, float scl, float mulk, float offk) {
    float e = __builtin_amdgcn_exp2f(scl * v);
    float s = __builtin_amdgcn_rcpf(1.0f + e);
    return mulk * s - offk;
}

// butterfly add via DPP: 0xB1=xor1, 0x4E=xor2, 0x141=xor4 (after 1,2), 0x140=xor8 (after 1,2,4)
template<int CTRL>
__device__ __forceinline__ float dpp_addf(float v) {
    int vi = __builtin_bit_cast(int, v);
    int sh = __builtin_amdgcn_update_dpp(0, vi, CTRL, 0xF, 0xF, true);
    return v + __builtin_bit_cast(float, sh);
}
// DPP move (no add): pull quad-neighbor's value
template<int CTRL>
__device__ __forceinline__ float dpp_movf(float v) {
    int vi = __builtin_bit_cast(int, v);
    int sh = __builtin_amdgcn_update_dpp(0, vi, CTRL, 0xF, 0xF, true);
    return __builtin_bit_cast(float, sh);
}

// R8-validated: barrier draining LDS only (no vmcnt drain).
__device__ __forceinline__ void block_sync_lds() {
    asm volatile("s_waitcnt lgkmcnt(0)\n\ts_barrier" ::: "memory");
}

__device__ __forceinline__ float hsum4(f32x4 v) { return (v.x + v.y) + (v.z + v.w); }

// ---- heavy role building blocks (R8/R12-validated geometry) ----
__device__ __forceinline__ void load_w_heavy(const float* __restrict__ w_ih,
                                             const float* __restrict__ w_hh,
                                             int j, int kc, f32x4 wt[4][8]) {
    #pragma unroll
    for (int r = 0; r < 4; ++r) {
        const int row = r * H_ + j;
        const float* base = (kc < 2) ? (w_ih + row * H_ + kc * 32)
                                     : (w_hh + row * H_ + (kc - 2) * 32);
        #pragma unroll
        for (int q = 0; q < 8; ++q)
            wt[r][q] = *(const f32x4*)(base + 4 * q);
    }
    #pragma unroll
    for (int r = 0; r < 4; ++r)
        #pragma unroll
        for (int q = 0; q < 8; ++q)
            asm volatile("" : "+v"(wt[r][q]));
}

__device__ __forceinline__ void dot4x32(const float* chunk, const f32x4 wt[4][8],
                                        float acc[4]) {
    const f32x4* xv = (const f32x4*)chunk;
    f32x4 a0 = {0,0,0,0}, a1 = {0,0,0,0}, a2 = {0,0,0,0}, a3 = {0,0,0,0};
    #pragma unroll
    for (int q = 0; q < 8; ++q) {
        f32x4 hq = xv[q];
        a0 = __builtin_elementwise_fma(wt[0][q], hq, a0);
        a1 = __builtin_elementwise_fma(wt[1][q], hq, a1);
        a2 = __builtin_elementwise_fma(wt[2][q], hq, a2);
        a3 = __builtin_elementwise_fma(wt[3][q], hq, a3);
    }
    acc[0] = hsum4(a0); acc[1] = hsum4(a1);
    acc[2] = hsum4(a2); acc[3] = hsum4(a3);
}

// select acc[kc] without dynamic indexing (cndmask chain, no alloca)
__device__ __forceinline__ float sel4(const float acc[4], int kc) {
    float v = acc[0];
    v = (kc == 1) ? acc[1] : v;
    v = (kc == 2) ? acc[2] : v;
    v = (kc == 3) ? acc[3] : v;
    return v;
}

// ---------------------------------------------------------------------------
// K1': diagonal TRIPLE [L0+L1+L2] (R12-validated structure + lane-split act).
// ---------------------------------------------------------------------------
__global__ __attribute__((amdgpu_flat_work_group_size(768, 768)))
void lstm_tri012(const float* __restrict__ x,      // [B,T]
                 float* __restrict__ hout,         // [B,T,64] = h_L2
                 const float* __restrict__ w_ih0,  // [256]
                 const float* __restrict__ whh0,
                 const float* __restrict__ bih0, const float* __restrict__ bhh0,
                 const float* __restrict__ wih1, const float* __restrict__ whh1,
                 const float* __restrict__ bih1, const float* __restrict__ bhh1,
                 const float* __restrict__ wih2, const float* __restrict__ whh2,
                 const float* __restrict__ bih2, const float* __restrict__ bhh2)
{
    const int b    = blockIdx.x;
    const int tid  = threadIdx.x;
    const int role = tid >> 8;      // 0=L0, 1=L1, 2=L2 (wave-uniform)
    const int loc  = tid & 255;
    const int kc   = loc & 3;
    const int j    = loc >> 2;      // hidden unit

    __shared__ __align__(16) float bufL0[2][80];    // L0 h: 4 chunks x 20
    __shared__ __align__(16) float bufL1[2][144];   // [x|h]: 4 chunks x 36
    __shared__ __align__(16) float bufL2[2][144];

    f32x4 wt[4][8];                 // L0 uses [4][4] portion
    float bias_me = 0.f, w0_me = 0.f;

    if (role == 0) {
        #pragma unroll
        for (int r = 0; r < 4; ++r) {
            const int row = r * H_ + j;
            const float* base = whh0 + row * H_ + kc * 16;
            #pragma unroll
            for (int q = 0; q < 4; ++q)
                wt[r][q] = *(const f32x4*)(base + 4 * q);
        }
        #pragma unroll
        for (int r = 0; r < 4; ++r)
            #pragma unroll
            for (int q = 0; q < 4; ++q)
                asm volatile("" : "+v"(wt[r][q]));
        bias_me = bih0[kc * H_ + j] + bhh0[kc * H_ + j];   // gate kc, unit j
        w0_me   = w_ih0[kc * H_ + j];
    } else {
        const float* wih = (role == 1) ? wih1 : wih2;
        const float* whh = (role == 1) ? whh1 : whh2;
        const float* bih = (role == 1) ? bih1 : bih2;
        const float* bhh = (role == 1) ? bhh1 : bhh2;
        load_w_heavy(wih, whh, j, kc, wt);
        bias_me = bih[kc * H_ + j] + bhh[kc * H_ + j];
    }
    // per-lane activation constants (gate kc==2 is tanh)
    const float scl  = (kc == 2) ? -2.8853900817779268f : -1.4426950408889634f;
    const float mulk = (kc == 2) ? 2.0f : 1.0f;
    const float offk = (kc == 2) ? 1.0f : 0.0f;

    float c_st = 0.f;
    float xt = (role == 0) ? x[(long)b * T_] : 0.f;

    float (*myBuf)[144] = (role == 1) ? bufL1 : bufL2;

    if (loc < H_) {
        const int u = loc;
        if (role == 0)      bufL0[0][(u >> 4) * 20 + (u & 15)] = 0.f;
        else if (role == 1) bufL1[1][(2 + (u >> 5)) * 36 + (u & 31)] = 0.f;
        else                bufL2[0][(2 + (u >> 5)) * 36 + (u & 31)] = 0.f;
    }
    block_sync_lds();

    for (int s = 0; s <= T_ + 1; ++s) {
        const int rb = s & 1, wb = rb ^ 1;
        const bool active = (role == 0) ? (s < T_)
                          : (role == 1) ? (s >= 1 && s <= T_)
                                        : (s >= 2);
        if (active) {
            float acc[4];
            float xn = 0.f;
            if (role == 0) {
                if (s + 1 < T_) xn = x[(long)b * T_ + s + 1];   // wave-uniform
                const f32x4* xv = (const f32x4*)&bufL0[rb][kc * 20];
                f32x4 h0 = xv[0], h1 = xv[1], h2 = xv[2], h3 = xv[3];
                f32x4 a0 = {0,0,0,0}, a1 = {0,0,0,0}, a2 = {0,0,0,0}, a3 = {0,0,0,0};
                a0 = __builtin_elementwise_fma(wt[0][0], h0, a0);
                a1 = __builtin_elementwise_fma(wt[1][0], h0, a1);
                a2 = __builtin_elementwise_fma(wt[2][0], h0, a2);
                a3 = __builtin_elementwise_fma(wt[3][0], h0, a3);
                a0 = __builtin_elementwise_fma(wt[0][1], h1, a0);
                a1 = __builtin_elementwise_fma(wt[1][1], h1, a1);
                a2 = __builtin_elementwise_fma(wt[2][1], h1, a2);
                a3 = __builtin_elementwise_fma(wt[3][1], h1, a3);
                a0 = __builtin_elementwise_fma(wt[0][2], h2, a0);
                a1 = __builtin_elementwise_fma(wt[1][2], h2, a1);
                a2 = __builtin_elementwise_fma(wt[2][2], h2, a2);
                a3 = __builtin_elementwise_fma(wt[3][2], h2, a3);
                a0 = __builtin_elementwise_fma(wt[0][3], h3, a0);
                a1 = __builtin_elementwise_fma(wt[1][3], h3, a1);
                a2 = __builtin_elementwise_fma(wt[2][3], h3, a2);
                a3 = __builtin_elementwise_fma(wt[3][3], h3, a3);
                acc[0] = hsum4(a0); acc[1] = hsum4(a1);
                acc[2] = hsum4(a2); acc[3] = hsum4(a3);
            } else {
                dot4x32(&myBuf[rb][kc * 36], wt, acc);
            }
            acc[0] = dpp_addf<0xB1>(acc[0]); acc[1] = dpp_addf<0xB1>(acc[1]);
            acc[2] = dpp_addf<0xB1>(acc[2]); acc[3] = dpp_addf<0xB1>(acc[3]);
            acc[0] = dpp_addf<0x4E>(acc[0]); acc[1] = dpp_addf<0x4E>(acc[1]);
            acc[2] = dpp_addf<0x4E>(acc[2]); acc[3] = dpp_addf<0x4E>(acc[3]);

            // ---- lane-split activation: lane kc does gate kc ----
            float v = sel4(acc, kc) + bias_me;
            if (role == 0) v += w0_me * xt;
            float act = gate_act(v, scl, mulk, offk);
            float f_v = dpp_movf<0xB1>(act);   // lane0 <- f (lane1)
            float g_v = dpp_movf<0x4E>(act);   // lane0 <- g (lane2)
            float o_v = dpp_movf<0x1B>(act);   // lane0 <- o (lane3)
            if (kc == 0) {
                c_st = f_v * c_st + act * g_v;
                float h = o_v * fast_tanh(c_st);
                if (role == 0) {
                    bufL0[wb][(j >> 4) * 20 + (j & 15)] = h;        // own h
                    bufL1[wb][(j >> 5) * 36 + (j & 31)] = h;        // L1's x
                } else {
                    myBuf[wb][(2 + (j >> 5)) * 36 + (j & 31)] = h;  // own h
                    if (role == 1)
                        bufL2[wb][(j >> 5) * 36 + (j & 31)] = h;    // L2's x
                    else
                        hout[((long)b * T_ + (s - 2)) * H_ + j] = h;
                }
            }
            if (role == 0) xt = xn;
        }
        block_sync_lds();
    }
}

// ---------------------------------------------------------------------------
// K2': diagonal PAIR [L3+L4] + MLP-HEAD role (R13). 576 threads:
//  role 0 = L3 (256 thr, heavy), role 1 = L4 (256 thr, heavy),
//  role 2 = head (64 thr = 1 wave): thread j owns W1 row j (64 pinned floats);
//  L4 feeds h through headBuf (LDS); head computes out[b,t] at t = s-2.
// L4 no longer writes global h; the separate MLP kernel is deleted.
// ---------------------------------------------------------------------------
__global__ __attribute__((amdgpu_flat_work_group_size(576, 576)))
void lstm_pair34_head(const float* __restrict__ xin,   // [B,T,64] h_L2
                      float* __restrict__ out,         // [B,T] final output
                      const float* __restrict__ wih3, const float* __restrict__ whh3,
                      const float* __restrict__ bih3, const float* __restrict__ bhh3,
                      const float* __restrict__ wih4, const float* __restrict__ whh4,
                      const float* __restrict__ bih4, const float* __restrict__ bhh4,
                      const float* __restrict__ W1,   // [64,64]
                      const float* __restrict__ b1,   // [64]
                      const float* __restrict__ W2,   // [64]
                      const float* __restrict__ b2)   // [1]
{
    const int b    = blockIdx.x;
    const int tid  = threadIdx.x;
    const int role = tid >> 8;      // 0=L3, 1=L4, 2=head (wave-uniform)
    const int loc  = tid & 255;
    const int kc   = loc & 3;
    const int j    = loc >> 2;

    __shared__ __align__(16) float bufL3[2][144];
    __shared__ __align__(16) float bufL4[2][144];
    __shared__ __align__(16) float headBuf[2][64];   // h_L4 rows for the head

    // ---------------- per-role setup ----------------
    f32x4 wt[4][8];                  // LSTM roles
    f32x4 w1r[16];                   // head: W1 row
    float bias_me = 0.f;
    float b1j = 0.f, w2j = 0.f, b2v = 0.f;

    if (role < 2) {
        const float* wih = (role == 0) ? wih3 : wih4;
        const float* whh = (role == 0) ? whh3 : whh4;
        const float* bih = (role == 0) ? bih3 : bih4;
        const float* bhh = (role == 0) ? bhh3 : bhh4;
        load_w_heavy(wih, whh, j, kc, wt);
        bias_me = bih[kc * H_ + j] + bhh[kc * H_ + j];
    } else {
        const int hj = loc & 63;     // head lane = W1 row
        #pragma unroll
        for (int q = 0; q < 16; ++q)
            w1r[q] = *(const f32x4*)(W1 + hj * H_ + 4 * q);
        #pragma unroll
        for (int q = 0; q < 16; ++q)
            asm volatile("" : "+v"(w1r[q]));
        b1j = b1[hj];
        w2j = W2[hj];
        b2v = b2[0];
    }
    const float scl  = (kc == 2) ? -2.8853900817779268f : -1.4426950408889634f;
    const float mulk = (kc == 2) ? 2.0f : 1.0f;
    const float offk = (kc == 2) ? 1.0f : 0.0f;

    float c_st = 0.f;

    float (*myBuf)[144] = (role == 0) ? bufL3 : bufL4;

    // LDS init: L3 reads parity 0 at s=0 (x row 0 + h=0); L4 parity 1 at s=1.
    if (tid < H_) {
        const int u = tid;
        bufL3[0][(u >> 5) * 36 + (u & 31)] = xin[(long)b * T_ * H_ + u];
        bufL3[0][(2 + (u >> 5)) * 36 + (u & 31)] = 0.f;
    } else if (tid < 128) {
        const int u = tid - 64;
        bufL4[1][(2 + (u >> 5)) * 36 + (u & 31)] = 0.f;
    }
    block_sync_lds();

    for (int s = 0; s <= T_ + 1; ++s) {
        const int rb = s & 1, wb = rb ^ 1;

        if (role < 2) {
            const bool active = (role == 0) ? (s < T_) : (s >= 1 && s <= T_);
            if (active) {
                // L3: prefetch next x row (kc==1 lanes)
                float xn = 0.f;
                if (role == 0 && kc == 1 && s + 1 < T_)
                    xn = xin[((long)b * T_ + s + 1) * H_ + j];

                float acc[4];
                dot4x32(&myBuf[rb][kc * 36], wt, acc);
                acc[0] = dpp_addf<0xB1>(acc[0]); acc[1] = dpp_addf<0xB1>(acc[1]);
                acc[2] = dpp_addf<0xB1>(acc[2]); acc[3] = dpp_addf<0xB1>(acc[3]);
                acc[0] = dpp_addf<0x4E>(acc[0]); acc[1] = dpp_addf<0x4E>(acc[1]);
                acc[2] = dpp_addf<0x4E>(acc[2]); acc[3] = dpp_addf<0x4E>(acc[3]);

                float v = sel4(acc, kc) + bias_me;
                float act = gate_act(v, scl, mulk, offk);
                float f_v = dpp_movf<0xB1>(act);
                float g_v = dpp_movf<0x4E>(act);
                float o_v = dpp_movf<0x1B>(act);
                if (kc == 0) {
                    c_st = f_v * c_st + act * g_v;
                    float h = o_v * fast_tanh(c_st);
                    myBuf[wb][(2 + (j >> 5)) * 36 + (j & 31)] = h;      // own h
                    if (role == 0)
                        bufL4[wb][(j >> 5) * 36 + (j & 31)] = h;        // L4's x
                    else
                        headBuf[wb][j] = h;                             // head's input
                }
                if (role == 0 && kc == 1)
                    bufL3[wb][(j >> 5) * 36 + (j & 31)] = xn;           // next x row
            }
        } else {
            // head: out[b, s-2] = W2 @ relu(W1 @ relu(h) + b1) + b2
            if (s >= 2) {
                const int hj = loc & 63;
                const f32x4* hv = (const f32x4*)&headBuf[rb][0];   // broadcast reads
                const f32x4 z4 = {0.f, 0.f, 0.f, 0.f};
                f32x4 a = z4;
                #pragma unroll
                for (int q = 0; q < 16; ++q) {
                    f32x4 h4 = __builtin_elementwise_max(hv[q], z4);   // relu(h)
                    a = __builtin_elementwise_fma(w1r[q], h4, a);
                }
                float y = fmaxf(b1j + hsum4(a), 0.f);
                float part = y * w2j;
                // full-wave (64-lane) sum
                part = dpp_addf<0xB1>(part);
                part = dpp_addf<0x4E>(part);
                part = dpp_addf<0x141>(part);   // xor4 (after 1,2)
                part = dpp_addf<0x140>(part);   // xor8 (row mirror, after 1,2,4)
                int pi = __builtin_bit_cast(int, part);
                float tsum =
                    __builtin_bit_cast(float, __builtin_amdgcn_readlane(pi, 0)) +
                    __builtin_bit_cast(float, __builtin_amdgcn_readlane(pi, 16)) +
                    __builtin_bit_cast(float, __builtin_amdgcn_readlane(pi, 32)) +
                    __builtin_bit_cast(float, __builtin_amdgcn_readlane(pi, 48));
                if (hj == 0)
                    out[(long)b * T_ + (s - 2)] = tsum + b2v;
            }
        }
        block_sync_lds();
    }
}

extern "C" void kernel_launch(void* const* d_in, const int* in_sizes, int n_in,
                              void* d_out, int out_size, void* d_ws, size_t ws_size,
                              hipStream_t stream) {
    const float* x     = (const float*)d_in[0];   // [B,T,1]
    const float* w_ih0 = (const float*)d_in[1];   // [256]
    const float* w_ihr = (const float*)d_in[2];   // [4,256,64]
    const float* w_hh  = (const float*)d_in[3];   // [5,256,64]
    const float* b_ih  = (const float*)d_in[4];   // [5,256]
    const float* b_hh  = (const float*)d_in[5];   // [5,256]
    const float* W1    = (const float*)d_in[6];   // [64,64]
    const float* b1    = (const float*)d_in[7];   // [64]
    const float* W2    = (const float*)d_in[8];   // [64]
    const float* b2    = (const float*)d_in[9];   // [1]
    // d_in[10] = future (0)

    float* out = (float*)d_out;                   // [B,T]
    float* buf = (float*)d_ws;                    // [B,T,64] fp32 = 64 MB (h_L2)

    const long LW = 4L * H_ * H_;   // 16384 floats per layer weight block
    const long LB = 4L * H_;        // 256 floats per layer bias block

    // K1': [L0+L1+L2] diagonal triple -> buf = h_L2
    lstm_tri012<<<dim3(B_), dim3(768), 0, stream>>>(
        x, buf,
        w_ih0, w_hh + 0 * LW, b_ih + 0 * LB, b_hh + 0 * LB,
        w_ihr + 0 * LW, w_hh + 1 * LW, b_ih + 1 * LB, b_hh + 1 * LB,
        w_ihr + 1 * LW, w_hh + 2 * LW, b_ih + 2 * LB, b_hh + 2 * LB);

    // K2': [L3+L4+head] -> out directly (no h_L4 materialization, no MLP pass)
    lstm_pair34_head<<<dim3(B_), dim3(576), 0, stream>>>(
        buf, out,
        w_ihr + 2 * LW, w_hh + 3 * LW, b_ih + 3 * LB, b_hh + 3 * LB,
        w_ihr + 3 * LW, w_hh + 4 * LW, b_ih + 4 * LB, b_hh + 4 * LB,
        W1, b1, W2, b2);
}

// Round 14
// 2034.582 us; speedup vs baseline: 3.6778x; 3.6778x over previous
//
#include <hip/hip_runtime.h>

#define B_ 256
#define T_ 1024
#define H_ 64

typedef float f32x2 __attribute__((ext_vector_type(2)));
typedef float f32x4 __attribute__((ext_vector_type(4)));

// fast sigmoid/tanh via v_exp_f32 + v_rcp_f32 (validated R2-R13: absmax 0.0)
__device__ __forceinline__ float fast_sigmoid(float x) {
    float e = __builtin_amdgcn_exp2f(-1.4426950408889634f * x);
    return __builtin_amdgcn_rcpf(1.0f + e);
}
__device__ __forceinline__ float fast_tanh(float x) {
    float e = __builtin_amdgcn_exp2f(2.8853900817779268f * x);
    return 1.0f - 2.0f * __builtin_amdgcn_rcpf(1.0f + e);
}

// butterfly add via DPP: 0xB1=xor1, 0x4E=xor2; 0x141=half-mirror(=xor4 after 1,2),
// 0x140=row-mirror(=xor8 after 1,2,4) — 64-lane head reduce validated R13.
template<int CTRL>
__device__ __forceinline__ float dpp_addf(float v) {
    int vi = __builtin_bit_cast(int, v);
    int sh = __builtin_amdgcn_update_dpp(0, vi, CTRL, 0xF, 0xF, true);
    return v + __builtin_bit_cast(float, sh);
}

// R8-validated: barrier draining LDS only (no vmcnt drain).
__device__ __forceinline__ void block_sync_lds() {
    asm volatile("s_waitcnt lgkmcnt(0)\n\ts_barrier" ::: "memory");
}

__device__ __forceinline__ float hsum4(f32x4 v) { return (v.x + v.y) + (v.z + v.w); }

// ---- heavy role building blocks (R8/R12-validated geometry) ----
__device__ __forceinline__ void load_w_heavy(const float* __restrict__ w_ih,
                                             const float* __restrict__ w_hh,
                                             int j, int kc, f32x4 wt[4][8]) {
    #pragma unroll
    for (int r = 0; r < 4; ++r) {
        const int row = r * H_ + j;
        const float* base = (kc < 2) ? (w_ih + row * H_ + kc * 32)
                                     : (w_hh + row * H_ + (kc - 2) * 32);
        #pragma unroll
        for (int q = 0; q < 8; ++q)
            wt[r][q] = *(const f32x4*)(base + 4 * q);
    }
}

__device__ __forceinline__ void dot4x32(const float* chunk, const f32x4 wt[4][8],
                                        float acc[4]) {
    const f32x4* xv = (const f32x4*)chunk;
    f32x4 a0 = {0,0,0,0}, a1 = {0,0,0,0}, a2 = {0,0,0,0}, a3 = {0,0,0,0};
    #pragma unroll
    for (int q = 0; q < 8; ++q) {
        f32x4 hq = xv[q];
        a0 = __builtin_elementwise_fma(wt[0][q], hq, a0);
        a1 = __builtin_elementwise_fma(wt[1][q], hq, a1);
        a2 = __builtin_elementwise_fma(wt[2][q], hq, a2);
        a3 = __builtin_elementwise_fma(wt[3][q], hq, a3);
    }
    acc[0] = hsum4(a0); acc[1] = hsum4(a1);
    acc[2] = hsum4(a2); acc[3] = hsum4(a3);
}

// ---------------------------------------------------------------------------
// K1': diagonal TRIPLE [L0+L1+L2] — R12's measured-1048us kernel VERBATIM.
// ---------------------------------------------------------------------------
__global__ __attribute__((amdgpu_flat_work_group_size(768, 768)))
void lstm_tri012(const float* __restrict__ x,      // [B,T]
                 float* __restrict__ hout,         // [B,T,64] = h_L2
                 const float* __restrict__ w_ih0,  // [256]
                 const float* __restrict__ whh0,
                 const float* __restrict__ bih0, const float* __restrict__ bhh0,
                 const float* __restrict__ wih1, const float* __restrict__ whh1,
                 const float* __restrict__ bih1, const float* __restrict__ bhh1,
                 const float* __restrict__ wih2, const float* __restrict__ whh2,
                 const float* __restrict__ bih2, const float* __restrict__ bhh2)
{
    const int b    = blockIdx.x;
    const int tid  = threadIdx.x;
    const int role = tid >> 8;      // 0=L0, 1=L1, 2=L2 (wave-uniform)
    const int loc  = tid & 255;
    const int kc   = loc & 3;
    const int j    = loc >> 2;      // hidden unit

    __shared__ __align__(16) float bufL0[2][80];    // L0 h: 4 chunks x 20
    __shared__ __align__(16) float bufL1[2][144];   // [x|h]: 4 chunks x 36
    __shared__ __align__(16) float bufL2[2][144];

    f32x4 wt[4][8];                 // L0 uses [4][4] portion
    float bias0 = 0.f, bias1 = 0.f, bias2 = 0.f, bias3 = 0.f;
    float w00 = 0.f, w01 = 0.f, w02 = 0.f, w03 = 0.f;

    if (role == 0) {
        #pragma unroll
        for (int r = 0; r < 4; ++r) {
            const int row = r * H_ + j;
            const float* base = whh0 + row * H_ + kc * 16;
            #pragma unroll
            for (int q = 0; q < 4; ++q)
                wt[r][q] = *(const f32x4*)(base + 4 * q);
        }
        #pragma unroll
        for (int r = 0; r < 4; ++r)
            #pragma unroll
            for (int q = 0; q < 4; ++q)
                asm volatile("" : "+v"(wt[r][q]));
        if (kc == 0) {
            bias0 = bih0[0*H_+j] + bhh0[0*H_+j];
            bias1 = bih0[1*H_+j] + bhh0[1*H_+j];
            bias2 = bih0[2*H_+j] + bhh0[2*H_+j];
            bias3 = bih0[3*H_+j] + bhh0[3*H_+j];
            w00 = w_ih0[0*H_+j]; w01 = w_ih0[1*H_+j];
            w02 = w_ih0[2*H_+j]; w03 = w_ih0[3*H_+j];
        }
    } else {
        const float* wih = (role == 1) ? wih1 : wih2;
        const float* whh = (role == 1) ? whh1 : whh2;
        const float* bih = (role == 1) ? bih1 : bih2;
        const float* bhh = (role == 1) ? bhh1 : bhh2;
        load_w_heavy(wih, whh, j, kc, wt);
        #pragma unroll
        for (int r = 0; r < 4; ++r)
            #pragma unroll
            for (int q = 0; q < 8; ++q)
                asm volatile("" : "+v"(wt[r][q]));
        if (kc == 0) {
            bias0 = bih[0*H_+j] + bhh[0*H_+j];
            bias1 = bih[1*H_+j] + bhh[1*H_+j];
            bias2 = bih[2*H_+j] + bhh[2*H_+j];
            bias3 = bih[3*H_+j] + bhh[3*H_+j];
        }
    }
    float c_st = 0.f;
    float xt = (role == 0) ? x[(long)b * T_] : 0.f;

    float (*myBuf)[144] = (role == 1) ? bufL1 : bufL2;

    // LDS init: L0 reads parity 0 at s=0; L1 parity 1 at s=1; L2 parity 0 at s=2.
    if (loc < H_) {
        const int u = loc;
        if (role == 0)      bufL0[0][(u >> 4) * 20 + (u & 15)] = 0.f;         // h_L0[-1]
        else if (role == 1) bufL1[1][(2 + (u >> 5)) * 36 + (u & 31)] = 0.f;   // h_L1[-1]
        else                bufL2[0][(2 + (u >> 5)) * 36 + (u & 31)] = 0.f;   // h_L2[-1]
    }
    block_sync_lds();

    for (int s = 0; s <= T_ + 1; ++s) {
        const int rb = s & 1, wb = rb ^ 1;
        const bool active = (role == 0) ? (s < T_)
                          : (role == 1) ? (s >= 1 && s <= T_)
                                        : (s >= 2);
        if (active) {
            if (role == 0) {
                float xn = 0.f;
                if (s + 1 < T_) xn = x[(long)b * T_ + s + 1];   // wave-uniform
                const f32x4* xv = (const f32x4*)&bufL0[rb][kc * 20];
                f32x4 h0 = xv[0], h1 = xv[1], h2 = xv[2], h3 = xv[3];
                f32x4 a0 = {0,0,0,0}, a1 = {0,0,0,0}, a2 = {0,0,0,0}, a3 = {0,0,0,0};
                a0 = __builtin_elementwise_fma(wt[0][0], h0, a0);
                a1 = __builtin_elementwise_fma(wt[1][0], h0, a1);
                a2 = __builtin_elementwise_fma(wt[2][0], h0, a2);
                a3 = __builtin_elementwise_fma(wt[3][0], h0, a3);
                a0 = __builtin_elementwise_fma(wt[0][1], h1, a0);
                a1 = __builtin_elementwise_fma(wt[1][1], h1, a1);
                a2 = __builtin_elementwise_fma(wt[2][1], h1, a2);
                a3 = __builtin_elementwise_fma(wt[3][1], h1, a3);
                a0 = __builtin_elementwise_fma(wt[0][2], h2, a0);
                a1 = __builtin_elementwise_fma(wt[1][2], h2, a1);
                a2 = __builtin_elementwise_fma(wt[2][2], h2, a2);
                a3 = __builtin_elementwise_fma(wt[3][2], h2, a3);
                a0 = __builtin_elementwise_fma(wt[0][3], h3, a0);
                a1 = __builtin_elementwise_fma(wt[1][3], h3, a1);
                a2 = __builtin_elementwise_fma(wt[2][3], h3, a2);
                a3 = __builtin_elementwise_fma(wt[3][3], h3, a3);
                float acc0 = hsum4(a0), acc1 = hsum4(a1);
                float acc2 = hsum4(a2), acc3 = hsum4(a3);
                acc0 = dpp_addf<0xB1>(acc0); acc1 = dpp_addf<0xB1>(acc1);
                acc2 = dpp_addf<0xB1>(acc2); acc3 = dpp_addf<0xB1>(acc3);
                acc0 = dpp_addf<0x4E>(acc0); acc1 = dpp_addf<0x4E>(acc1);
                acc2 = dpp_addf<0x4E>(acc2); acc3 = dpp_addf<0x4E>(acc3);
                if (kc == 0) {
                    float i_ = fast_sigmoid(acc0 + bias0 + w00 * xt);
                    float f_ = fast_sigmoid(acc1 + bias1 + w01 * xt);
                    float g_ = fast_tanh   (acc2 + bias2 + w02 * xt);
                    float o_ = fast_sigmoid(acc3 + bias3 + w03 * xt);
                    c_st = f_ * c_st + i_ * g_;
                    float h = o_ * fast_tanh(c_st);
                    bufL0[wb][(j >> 4) * 20 + (j & 15)] = h;            // own h
                    bufL1[wb][(j >> 5) * 36 + (j & 31)] = h;            // L1's x
                }
                xt = xn;
            } else {
                float acc[4];
                dot4x32(&myBuf[rb][kc * 36], wt, acc);
                acc[0] = dpp_addf<0xB1>(acc[0]); acc[1] = dpp_addf<0xB1>(acc[1]);
                acc[2] = dpp_addf<0xB1>(acc[2]); acc[3] = dpp_addf<0xB1>(acc[3]);
                acc[0] = dpp_addf<0x4E>(acc[0]); acc[1] = dpp_addf<0x4E>(acc[1]);
                acc[2] = dpp_addf<0x4E>(acc[2]); acc[3] = dpp_addf<0x4E>(acc[3]);
                if (kc == 0) {
                    float i_ = fast_sigmoid(acc[0] + bias0);
                    float f_ = fast_sigmoid(acc[1] + bias1);
                    float g_ = fast_tanh   (acc[2] + bias2);
                    float o_ = fast_sigmoid(acc[3] + bias3);
                    c_st = f_ * c_st + i_ * g_;
                    float h = o_ * fast_tanh(c_st);
                    myBuf[wb][(2 + (j >> 5)) * 36 + (j & 31)] = h;      // own h
                    if (role == 1)
                        bufL2[wb][(j >> 5) * 36 + (j & 31)] = h;        // L2's x
                    else
                        hout[((long)b * T_ + (s - 2)) * H_ + j] = h;
                }
            }
        }
        block_sync_lds();
    }
}

// ---------------------------------------------------------------------------
// K2': diagonal PAIR [L3+L4] + fused MLP head (R14). 576 threads = 9 waves:
//  role 0 = L3 (4 waves), role 1 = L4 (4 waves), role 2 = head (1 wave).
// REGISTER ALIASING (the R13 fix): the head reuses the SAME pinned wt[4][8]
// array — W1 row hj lives in wt[0][0..7] + wt[1][0..7], wt[2..3] zeroed.
// Static pinned floats = 128 for every role (R12's proven allocation).
// L4's h goes to headBuf (LDS) instead of global; head computes out[b,s-2]
// via full-wave DPP reduce (R13-correctness-proven). K2 writes ONLY `out`.
// ---------------------------------------------------------------------------
__global__ __attribute__((amdgpu_flat_work_group_size(576, 576)))
void lstm_pair34_head(const float* __restrict__ xin,   // [B,T,64] h_L2
                      float* __restrict__ out,         // [B,T] final output
                      const float* __restrict__ wih3, const float* __restrict__ whh3,
                      const float* __restrict__ bih3, const float* __restrict__ bhh3,
                      const float* __restrict__ wih4, const float* __restrict__ whh4,
                      const float* __restrict__ bih4, const float* __restrict__ bhh4,
                      const float* __restrict__ W1,   // [64,64]
                      const float* __restrict__ b1,   // [64]
                      const float* __restrict__ W2,   // [64]
                      const float* __restrict__ b2)   // [1]
{
    const int b    = blockIdx.x;
    const int tid  = threadIdx.x;
    const int role = tid >> 8;      // 0=L3, 1=L4, 2=head (wave-uniform)
    const int loc  = tid & 255;
    const int kc   = loc & 3;
    const int j    = loc >> 2;

    __shared__ __align__(16) float bufL3[2][144];
    __shared__ __align__(16) float bufL4[2][144];
    __shared__ __align__(16) float headBuf[2][64];   // h_L4 rows for the head

    // ---- shared pinned array: LSTM weights OR W1 row (aliased) ----
    f32x4 wt[4][8];
    float bias0 = 0.f, bias1 = 0.f, bias2 = 0.f, bias3 = 0.f;
    float b1j = 0.f, w2j = 0.f, b2v = 0.f;

    if (role < 2) {
        const float* wih = (role == 0) ? wih3 : wih4;
        const float* whh = (role == 0) ? whh3 : whh4;
        const float* bih = (role == 0) ? bih3 : bih4;
        const float* bhh = (role == 0) ? bhh3 : bhh4;
        load_w_heavy(wih, whh, j, kc, wt);
        if (kc == 0) {
            bias0 = bih[0*H_+j] + bhh[0*H_+j];
            bias1 = bih[1*H_+j] + bhh[1*H_+j];
            bias2 = bih[2*H_+j] + bhh[2*H_+j];
            bias3 = bih[3*H_+j] + bhh[3*H_+j];
        }
    } else {
        const int hj = loc & 63;     // head lane = W1 row
        #pragma unroll
        for (int q = 0; q < 8; ++q) {
            wt[0][q] = *(const f32x4*)(W1 + hj * H_ + 4 * q);        // W1[hj][0..31]
            wt[1][q] = *(const f32x4*)(W1 + hj * H_ + 32 + 4 * q);   // W1[hj][32..63]
            wt[2][q] = (f32x4){0.f, 0.f, 0.f, 0.f};
            wt[3][q] = (f32x4){0.f, 0.f, 0.f, 0.f};
        }
        b1j = b1[hj];
        w2j = W2[hj];
        b2v = b2[0];
    }
    #pragma unroll
    for (int r = 0; r < 4; ++r)
        #pragma unroll
        for (int q = 0; q < 8; ++q)
            asm volatile("" : "+v"(wt[r][q]));

    float c_st = 0.f;

    float (*myBuf)[144] = (role == 0) ? bufL3 : bufL4;

    // LDS init: L3 reads parity 0 at s=0 (x row 0 + h=0); L4 parity 1 at s=1;
    // head first reads parity 0 at s=2 (written by L4 during s=1).
    if (tid < H_) {
        const int u = tid;
        bufL3[0][(u >> 5) * 36 + (u & 31)] = xin[(long)b * T_ * H_ + u];
        bufL3[0][(2 + (u >> 5)) * 36 + (u & 31)] = 0.f;
    } else if (tid < 128) {
        const int u = tid - 64;
        bufL4[1][(2 + (u >> 5)) * 36 + (u & 31)] = 0.f;
    }
    block_sync_lds();

    for (int s = 0; s <= T_ + 1; ++s) {
        const int rb = s & 1, wb = rb ^ 1;

        if (role < 2) {
            const bool active = (role == 0) ? (s < T_) : (s >= 1 && s <= T_);
            if (active) {
                // L3: prefetch next x row (kc==1 lanes, one float each)
                float xn = 0.f;
                if (role == 0 && kc == 1 && s + 1 < T_)
                    xn = xin[((long)b * T_ + s + 1) * H_ + j];

                float acc[4];
                dot4x32(&myBuf[rb][kc * 36], wt, acc);
                acc[0] = dpp_addf<0xB1>(acc[0]); acc[1] = dpp_addf<0xB1>(acc[1]);
                acc[2] = dpp_addf<0xB1>(acc[2]); acc[3] = dpp_addf<0xB1>(acc[3]);
                acc[0] = dpp_addf<0x4E>(acc[0]); acc[1] = dpp_addf<0x4E>(acc[1]);
                acc[2] = dpp_addf<0x4E>(acc[2]); acc[3] = dpp_addf<0x4E>(acc[3]);

                if (kc == 0) {
                    float i_ = fast_sigmoid(acc[0] + bias0);
                    float f_ = fast_sigmoid(acc[1] + bias1);
                    float g_ = fast_tanh   (acc[2] + bias2);
                    float o_ = fast_sigmoid(acc[3] + bias3);
                    c_st = f_ * c_st + i_ * g_;
                    float h = o_ * fast_tanh(c_st);
                    myBuf[wb][(2 + (j >> 5)) * 36 + (j & 31)] = h;      // own h
                    if (role == 0)
                        bufL4[wb][(j >> 5) * 36 + (j & 31)] = h;        // L4's x
                    else
                        headBuf[wb][j] = h;                             // head's input
                }
                if (role == 0 && kc == 1)
                    bufL3[wb][(j >> 5) * 36 + (j & 31)] = xn;           // next x row
            }
        } else {
            // head: out[b, s-2] = W2 @ relu(W1 @ relu(h_L4[s-2]) + b1) + b2
            if (s >= 2) {
                const int hj = loc & 63;
                const f32x4* hv = (const f32x4*)&headBuf[rb][0];   // broadcast reads
                const f32x4 z4 = {0.f, 0.f, 0.f, 0.f};
                f32x4 a = z4;
                #pragma unroll
                for (int q = 0; q < 8; ++q) {
                    f32x4 h4 = __builtin_elementwise_max(hv[q], z4);       // relu
                    a = __builtin_elementwise_fma(wt[0][q], h4, a);
                }
                #pragma unroll
                for (int q = 0; q < 8; ++q) {
                    f32x4 h4 = __builtin_elementwise_max(hv[8 + q], z4);   // relu
                    a = __builtin_elementwise_fma(wt[1][q], h4, a);
                }
                float y = fmaxf(b1j + hsum4(a), 0.f);
                float part = y * w2j;
                // full-wave (64-lane) sum: xor1,2 then half/row mirrors + readlanes
                part = dpp_addf<0xB1>(part);
                part = dpp_addf<0x4E>(part);
                part = dpp_addf<0x141>(part);
                part = dpp_addf<0x140>(part);
                int pi = __builtin_bit_cast(int, part);
                float tsum =
                    __builtin_bit_cast(float, __builtin_amdgcn_readlane(pi, 0)) +
                    __builtin_bit_cast(float, __builtin_amdgcn_readlane(pi, 16)) +
                    __builtin_bit_cast(float, __builtin_amdgcn_readlane(pi, 32)) +
                    __builtin_bit_cast(float, __builtin_amdgcn_readlane(pi, 48));
                if (hj == 0)
                    out[(long)b * T_ + (s - 2)] = tsum + b2v;
            }
        }
        block_sync_lds();
    }
}

extern "C" void kernel_launch(void* const* d_in, const int* in_sizes, int n_in,
                              void* d_out, int out_size, void* d_ws, size_t ws_size,
                              hipStream_t stream) {
    const float* x     = (const float*)d_in[0];   // [B,T,1]
    const float* w_ih0 = (const float*)d_in[1];   // [256]
    const float* w_ihr = (const float*)d_in[2];   // [4,256,64]
    const float* w_hh  = (const float*)d_in[3];   // [5,256,64]
    const float* b_ih  = (const float*)d_in[4];   // [5,256]
    const float* b_hh  = (const float*)d_in[5];   // [5,256]
    const float* W1    = (const float*)d_in[6];   // [64,64]
    const float* b1    = (const float*)d_in[7];   // [64]
    const float* W2    = (const float*)d_in[8];   // [64]
    const float* b2    = (const float*)d_in[9];   // [1]
    // d_in[10] = future (0)

    float* out = (float*)d_out;                   // [B,T]
    float* buf = (float*)d_ws;                    // [B,T,64] fp32 = 64 MB (h_L2)

    const long LW = 4L * H_ * H_;   // 16384 floats per layer weight block
    const long LB = 4L * H_;        // 256 floats per layer bias block

    // K1': [L0+L1+L2] diagonal triple -> buf = h_L2 (R12-proven, 1048 us)
    lstm_tri012<<<dim3(B_), dim3(768), 0, stream>>>(
        x, buf,
        w_ih0, w_hh + 0 * LW, b_ih + 0 * LB, b_hh + 0 * LB,
        w_ihr + 0 * LW, w_hh + 1 * LW, b_ih + 1 * LB, b_hh + 1 * LB,
        w_ihr + 1 * LW, w_hh + 2 * LW, b_ih + 2 * LB, b_hh + 2 * LB);

    // K2': [L3+L4+head] -> out directly (no h_L4 materialization, no MLP pass)
    lstm_pair34_head<<<dim3(B_), dim3(576), 0, stream>>>(
        buf, out,
        w_ihr + 2 * LW, w_hh + 3 * LW, b_ih + 3 * LB, b_hh + 3 * LB,
        w_ihr + 3 * LW, w_hh + 4 * LW, b_ih + 4 * LB, b_hh + 4 * LB,
        W1, b1, W2, b2);
}